// Round 1
// baseline (739.267 us; speedup 1.0000x reference)
//
#include <hip/hip_runtime.h>
#include <math.h>

#define HH 512
#define PP 256
#define LSEQ 4096
#define BB 8
#define MTOT (BB*LSEQ)   // 32768
#define N2P 512          // 2*P

// ---------- small prep kernels ----------

__global__ void prep_lambda_k(const float* __restrict__ lre, const float* __restrict__ lim,
                              const float* __restrict__ logd, float2* __restrict__ lamb) {
    int p = threadIdx.x;
    if (p < PP) {
        float delta = expf(logd[p]);
        float er = expf(lre[p] * delta);
        float th = lim[p] * delta;
        lamb[p] = make_float2(er * cosf(th), er * sinf(th));
    }
}

// W1[h][p]     = Re(B_bar[p][h]),  W1[h][P+p] = Im(B_bar[p][h])
// B_bar = ((lambda_bar - 1)/lam) * (B_re + i B_im)
__global__ void prep_w1_k(const float* __restrict__ lre, const float* __restrict__ lim,
                          const float* __restrict__ logd,
                          const float* __restrict__ Bre, const float* __restrict__ Bim,
                          float* __restrict__ W1) {
    int idx = blockIdx.x * 256 + threadIdx.x;   // over P*H
    if (idx >= PP * HH) return;
    int p = idx >> 9;          // /512
    int h = idx & (HH - 1);
    float delta = expf(logd[p]);
    float lr = lre[p], li = lim[p];
    float er = expf(lr * delta);
    float th = li * delta;
    float lbr = er * cosf(th), lbi = er * sinf(th);
    float a = lbr - 1.0f, b = lbi;
    float n2 = lr * lr + li * li;
    float gr = (a * lr + b * li) / n2;
    float gi = (b * lr - a * li) / n2;
    float br = Bre[idx], bi = Bim[idx];
    W1[h * N2P + p]      = gr * br - gi * bi;
    W1[h * N2P + PP + p] = gr * bi + gi * br;
}

// W2[k][h]: k<P -> 2*C_re[h][k] ; k>=P -> -2*C_im[h][k-P]
__global__ void prep_w2_k(const float* __restrict__ Cre, const float* __restrict__ Cim,
                          float* __restrict__ W2) {
    int idx = blockIdx.x * 256 + threadIdx.x;   // over 2P*H
    if (idx >= N2P * HH) return;
    int k = idx >> 9;
    int h = idx & (HH - 1);
    float v;
    if (k < PP) v = 2.0f * Cre[h * PP + k];
    else        v = -2.0f * Cim[h * PP + (k - PP)];
    W2[k * HH + h] = v;
}

// ---------- fp32 tiled GEMM: C[M x 512] = A[M x 512] @ W[512 x 512] (+ D*u) ----------

template<bool EPI>
__global__ __launch_bounds__(256) void gemm_tile(const float* __restrict__ A,
                                                 const float* __restrict__ W,
                                                 float* __restrict__ C,
                                                 const float* __restrict__ u,
                                                 const float* __restrict__ D) {
    __shared__ float As[32][68];   // transposed: As[k][row]
    __shared__ float Bs[32][68];   // Bs[k][col]
    const int tid = threadIdx.x;
    const int tx = tid & 15, ty = tid >> 4;
    const int m0 = blockIdx.y * 64;
    const int n0 = blockIdx.x * 64;

    float acc[4][4] = {};

    for (int k0 = 0; k0 < 512; k0 += 32) {
        // A tile: 64 rows x 32 cols -> 512 float4
        #pragma unroll
        for (int li = tid; li < 512; li += 256) {
            int row = li >> 3;
            int c4 = (li & 7) << 2;
            const float4 v = *(const float4*)&A[(size_t)(m0 + row) * 512 + k0 + c4];
            As[c4 + 0][row] = v.x;
            As[c4 + 1][row] = v.y;
            As[c4 + 2][row] = v.z;
            As[c4 + 3][row] = v.w;
        }
        // W tile: 32 rows x 64 cols -> 512 float4
        #pragma unroll
        for (int li = tid; li < 512; li += 256) {
            int row = li >> 4;
            int c4 = (li & 15) << 2;
            *(float4*)&Bs[row][c4] = *(const float4*)&W[(size_t)(k0 + row) * 512 + n0 + c4];
        }
        __syncthreads();
        #pragma unroll
        for (int k = 0; k < 32; ++k) {
            const float4 a4 = *(const float4*)&As[k][ty << 2];
            const float4 b4 = *(const float4*)&Bs[k][tx << 2];
            float a[4] = {a4.x, a4.y, a4.z, a4.w};
            float b[4] = {b4.x, b4.y, b4.z, b4.w};
            #pragma unroll
            for (int i = 0; i < 4; ++i)
                #pragma unroll
                for (int j = 0; j < 4; ++j)
                    acc[i][j] += a[i] * b[j];
        }
        __syncthreads();
    }

    const int col = n0 + (tx << 2);
    #pragma unroll
    for (int i = 0; i < 4; ++i) {
        const int row = m0 + (ty << 2) + i;
        float4 o = make_float4(acc[i][0], acc[i][1], acc[i][2], acc[i][3]);
        if (EPI) {
            const float4 uv = *(const float4*)&u[(size_t)row * 512 + col];
            const float4 dv = *(const float4*)&D[col];
            o.x += dv.x * uv.x;
            o.y += dv.y * uv.y;
            o.z += dv.z * uv.z;
            o.w += dv.w * uv.w;
        }
        *(float4*)&C[(size_t)row * 512 + col] = o;
    }
}

// ---------- chunked complex scan: x_l = L * x_{l-1} + Bu_l ----------
// one block per (b,p); 256 threads x 16 steps = 4096
__global__ __launch_bounds__(256) void scan_k(const float* __restrict__ Bu,
                                              float* __restrict__ Xs,
                                              const float2* __restrict__ lamb) {
    const int b = blockIdx.x >> 8;
    const int p = blockIdx.x & 255;
    const int t = threadIdx.x;
    const float2 L = lamb[p];

    const size_t rowbase = (size_t)(b * LSEQ + t * 16) * 512;

    float2 bu[16];
    float sr = 0.f, si = 0.f;
    #pragma unroll
    for (int j = 0; j < 16; ++j) {
        size_t r = rowbase + (size_t)j * 512;
        float re = Bu[r + p];
        float im = Bu[r + PP + p];
        bu[j] = make_float2(re, im);
        float nsr = L.x * sr - L.y * si + re;
        si = L.x * si + L.y * sr + im;
        sr = nsr;
    }

    __shared__ float cr[256], ci[256];
    cr[t] = sr; ci[t] = si;
    __syncthreads();

    // w = L^16 via 4 squarings
    float wr = L.x, wi = L.y;
    #pragma unroll
    for (int q = 0; q < 4; ++q) { float nr = wr * wr - wi * wi; wi = 2.f * wr * wi; wr = nr; }

    for (int off = 1; off < 256; off <<= 1) {
        float pr = 0.f, pi = 0.f;
        const bool has = (t >= off);
        if (has) { pr = cr[t - off]; pi = ci[t - off]; }
        __syncthreads();
        if (has) {
            sr += wr * pr - wi * pi;
            si += wr * pi + wi * pr;
            cr[t] = sr; ci[t] = si;
        }
        __syncthreads();
        float nr = wr * wr - wi * wi; wi = 2.f * wr * wi; wr = nr;
    }

    float xr = 0.f, xi = 0.f;
    if (t > 0) { xr = cr[t - 1]; xi = ci[t - 1]; }

    #pragma unroll
    for (int j = 0; j < 16; ++j) {
        float nr = L.x * xr - L.y * xi + bu[j].x;
        xi = L.x * xi + L.y * xr + bu[j].y;
        xr = nr;
        size_t r = rowbase + (size_t)j * 512;
        Xs[r + p] = xr;
        Xs[r + PP + p] = xi;
    }
}

// ---------- launch ----------

extern "C" void kernel_launch(void* const* d_in, const int* in_sizes, int n_in,
                              void* d_out, int out_size, void* d_ws, size_t ws_size,
                              hipStream_t stream) {
    const float* u    = (const float*)d_in[0];
    const float* lre  = (const float*)d_in[1];
    const float* lim  = (const float*)d_in[2];
    const float* Bre  = (const float*)d_in[3];
    const float* Bim  = (const float*)d_in[4];
    const float* Cre  = (const float*)d_in[5];
    const float* Cim  = (const float*)d_in[6];
    const float* Dv   = (const float*)d_in[7];
    const float* logd = (const float*)d_in[8];
    float* out = (float*)d_out;

    char* ws = (char*)d_ws;
    float*  W1   = (float*)ws;                          // 1 MB
    float*  W2   = (float*)(ws + (1 << 20));            // 1 MB
    float2* lamb = (float2*)(ws + (2 << 20));           // 2 KB
    float*  Xs   = (float*)(ws + (2 << 20) + 4096);     // 64 MB

    prep_lambda_k<<<1, 256, 0, stream>>>(lre, lim, logd, lamb);
    prep_w1_k<<<(PP * HH) / 256, 256, 0, stream>>>(lre, lim, logd, Bre, Bim, W1);
    prep_w2_k<<<(N2P * HH) / 256, 256, 0, stream>>>(Cre, Cim, W2);

    // GEMM1: Bu (packed re|im) -> d_out
    gemm_tile<false><<<dim3(8, 512), 256, 0, stream>>>(u, W1, out, nullptr, nullptr);
    // scan: d_out -> Xs
    scan_k<<<BB * PP, 256, 0, stream>>>(out, Xs, lamb);
    // GEMM2: y -> d_out  (+ D*u epilogue)
    gemm_tile<true><<<dim3(8, 512), 256, 0, stream>>>(Xs, W2, out, u, Dv);
}

// Round 2
// 503.895 us; speedup vs baseline: 1.4671x; 1.4671x over previous
//
#include <hip/hip_runtime.h>
#include <math.h>

#define HH 512
#define PP 256
#define LSEQ 4096
#define BB 8
#define MTOT (BB*LSEQ)   // 32768
#define N2P 512          // 2*P

// ---------- small prep kernels ----------

// W1[h][p]     = Re(B_bar[p][h]),  W1[h][P+p] = Im(B_bar[p][h])
__global__ void prep_w1_k(const float* __restrict__ lre, const float* __restrict__ lim,
                          const float* __restrict__ logd,
                          const float* __restrict__ Bre, const float* __restrict__ Bim,
                          float* __restrict__ W1, float2* __restrict__ lamb) {
    int idx = blockIdx.x * 256 + threadIdx.x;   // over P*H
    if (idx >= PP * HH) return;
    int p = idx >> 9;          // /512
    int h = idx & (HH - 1);
    float delta = expf(logd[p]);
    float lr = lre[p], li = lim[p];
    float er = expf(lr * delta);
    float th = li * delta;
    float lbr = er * cosf(th), lbi = er * sinf(th);
    if (h == 0) lamb[p] = make_float2(lbr, lbi);
    float a = lbr - 1.0f, b = lbi;
    float n2 = lr * lr + li * li;
    float gr = (a * lr + b * li) / n2;
    float gi = (b * lr - a * li) / n2;
    float br = Bre[idx], bi = Bim[idx];
    W1[h * N2P + p]      = gr * br - gi * bi;
    W1[h * N2P + PP + p] = gr * bi + gi * br;
}

// W2[k][h]: k<P -> 2*C_re[h][k] ; k>=P -> -2*C_im[h][k-P]
__global__ void prep_w2_k(const float* __restrict__ Cre, const float* __restrict__ Cim,
                          float* __restrict__ W2) {
    int idx = blockIdx.x * 256 + threadIdx.x;   // over 2P*H
    if (idx >= N2P * HH) return;
    int k = idx >> 9;
    int h = idx & (HH - 1);
    float v;
    if (k < PP) v = 2.0f * Cre[h * PP + k];
    else        v = -2.0f * Cim[h * PP + (k - PP)];
    W2[k * HH + h] = v;
}

// ---------- GEMM1: T1[r][m] = sum_h W1[h][r] * u[m][h] ----------
// output transposed: rows r in [0,512) (re|im packed), cols m in [0,32768)
__global__ __launch_bounds__(256) void gemm1_t(const float* __restrict__ u,
                                               const float* __restrict__ W1,
                                               float* __restrict__ T1) {
    __shared__ float As[32][68];   // As[k][r]  (A' = W1^T, stored direct)
    __shared__ float Bs[32][68];   // Bs[k][m]  (B' = u^T, staged with transpose)
    const int tid = threadIdx.x;
    const int tx = tid & 15, ty = tid >> 4;
    const int m0 = blockIdx.x * 64;   // cols (sequence position)
    const int r0 = blockIdx.y * 64;   // rows (state re/im)

    float acc[4][4] = {};

    for (int k0 = 0; k0 < 512; k0 += 32) {
        // A' tile: W1 rows k0..k0+32, cols r0..r0+64 -> direct float4
        #pragma unroll
        for (int li = tid; li < 512; li += 256) {
            int kk = li >> 4;
            int c4 = (li & 15) << 2;
            *(float4*)&As[kk][c4] = *(const float4*)&W1[(size_t)(k0 + kk) * 512 + r0 + c4];
        }
        // B' tile: u rows m0..m0+64, cols k0..k0+32 -> transpose scatter
        #pragma unroll
        for (int li = tid; li < 512; li += 256) {
            int col = li >> 3;
            int c4 = (li & 7) << 2;
            const float4 v = *(const float4*)&u[(size_t)(m0 + col) * 512 + k0 + c4];
            Bs[c4 + 0][col] = v.x;
            Bs[c4 + 1][col] = v.y;
            Bs[c4 + 2][col] = v.z;
            Bs[c4 + 3][col] = v.w;
        }
        __syncthreads();
        #pragma unroll
        for (int k = 0; k < 32; ++k) {
            const float4 a4 = *(const float4*)&As[k][ty << 2];
            const float4 b4 = *(const float4*)&Bs[k][tx << 2];
            float a[4] = {a4.x, a4.y, a4.z, a4.w};
            float b[4] = {b4.x, b4.y, b4.z, b4.w};
            #pragma unroll
            for (int i = 0; i < 4; ++i)
                #pragma unroll
                for (int j = 0; j < 4; ++j)
                    acc[i][j] += a[i] * b[j];
        }
        __syncthreads();
    }

    #pragma unroll
    for (int i = 0; i < 4; ++i) {
        const int r = r0 + (ty << 2) + i;
        float4 o = make_float4(acc[i][0], acc[i][1], acc[i][2], acc[i][3]);
        *(float4*)&T1[(size_t)r * MTOT + m0 + (tx << 2)] = o;
    }
}

// ---------- GEMM2: y[m][h] = sum_k Xs'[k][m] * W2[k][h] + D[h]*u[m][h] ----------
__global__ __launch_bounds__(256) void gemm2_t(const float* __restrict__ Xs,
                                               const float* __restrict__ W2,
                                               float* __restrict__ C,
                                               const float* __restrict__ u,
                                               const float* __restrict__ D) {
    __shared__ float As[32][68];   // As[k][m]  (Xs' already k-major: direct float4)
    __shared__ float Bs[32][68];   // Bs[k][h]  (W2 k-major: direct float4)
    const int tid = threadIdx.x;
    const int tx = tid & 15, ty = tid >> 4;
    const int m0 = blockIdx.y * 64;   // rows (sequence position)
    const int n0 = blockIdx.x * 64;   // cols (h)

    float acc[4][4] = {};

    for (int k0 = 0; k0 < 512; k0 += 32) {
        #pragma unroll
        for (int li = tid; li < 512; li += 256) {
            int kk = li >> 4;
            int c4 = (li & 15) << 2;
            *(float4*)&As[kk][c4] = *(const float4*)&Xs[(size_t)(k0 + kk) * MTOT + m0 + c4];
            *(float4*)&Bs[kk][c4] = *(const float4*)&W2[(size_t)(k0 + kk) * 512 + n0 + c4];
        }
        __syncthreads();
        #pragma unroll
        for (int k = 0; k < 32; ++k) {
            const float4 a4 = *(const float4*)&As[k][ty << 2];
            const float4 b4 = *(const float4*)&Bs[k][tx << 2];
            float a[4] = {a4.x, a4.y, a4.z, a4.w};
            float b[4] = {b4.x, b4.y, b4.z, b4.w};
            #pragma unroll
            for (int i = 0; i < 4; ++i)
                #pragma unroll
                for (int j = 0; j < 4; ++j)
                    acc[i][j] += a[i] * b[j];
        }
        __syncthreads();
    }

    const int col = n0 + (tx << 2);
    #pragma unroll
    for (int i = 0; i < 4; ++i) {
        const int row = m0 + (ty << 2) + i;
        float4 o = make_float4(acc[i][0], acc[i][1], acc[i][2], acc[i][3]);
        const float4 uv = *(const float4*)&u[(size_t)row * 512 + col];
        const float4 dv = *(const float4*)&D[col];
        o.x += dv.x * uv.x;
        o.y += dv.y * uv.y;
        o.z += dv.z * uv.z;
        o.w += dv.w * uv.w;
        *(float4*)&C[(size_t)row * 512 + col] = o;
    }
}

// ---------- coalesced chunked complex scan over contiguous chains ----------
// T1 rows p (re) and P+p (im), chain segment [b*4096, (b+1)*4096)
__global__ __launch_bounds__(256) void scan_k(const float* __restrict__ T1,
                                              float* __restrict__ Xs,
                                              const float2* __restrict__ lamb) {
    const int b = blockIdx.x >> 8;
    const int p = blockIdx.x & 255;
    const int t = threadIdx.x;
    const float2 L = lamb[p];

    const size_t baseRe = (size_t)p * MTOT + (size_t)b * LSEQ + t * 16;
    const size_t baseIm = (size_t)(PP + p) * MTOT + (size_t)b * LSEQ + t * 16;

    float re[16], im[16];
    #pragma unroll
    for (int q = 0; q < 4; ++q) {
        const float4 vr = *(const float4*)&T1[baseRe + q * 4];
        const float4 vi = *(const float4*)&T1[baseIm + q * 4];
        re[q*4+0] = vr.x; re[q*4+1] = vr.y; re[q*4+2] = vr.z; re[q*4+3] = vr.w;
        im[q*4+0] = vi.x; im[q*4+1] = vi.y; im[q*4+2] = vi.z; im[q*4+3] = vi.w;
    }

    float sr = 0.f, si = 0.f;
    #pragma unroll
    for (int j = 0; j < 16; ++j) {
        float nsr = L.x * sr - L.y * si + re[j];
        si = L.x * si + L.y * sr + im[j];
        sr = nsr;
    }

    __shared__ float cr[256], ci[256];
    cr[t] = sr; ci[t] = si;
    __syncthreads();

    // w = L^16 via 4 squarings
    float wr = L.x, wi = L.y;
    #pragma unroll
    for (int q = 0; q < 4; ++q) { float nr = wr * wr - wi * wi; wi = 2.f * wr * wi; wr = nr; }

    for (int off = 1; off < 256; off <<= 1) {
        float pr = 0.f, pi = 0.f;
        const bool has = (t >= off);
        if (has) { pr = cr[t - off]; pi = ci[t - off]; }
        __syncthreads();
        if (has) {
            sr += wr * pr - wi * pi;
            si += wr * pi + wi * pr;
            cr[t] = sr; ci[t] = si;
        }
        __syncthreads();
        float nr = wr * wr - wi * wi; wi = 2.f * wr * wi; wr = nr;
    }

    float xr = 0.f, xi = 0.f;
    if (t > 0) { xr = cr[t - 1]; xi = ci[t - 1]; }

    #pragma unroll
    for (int j = 0; j < 16; ++j) {
        float nr = L.x * xr - L.y * xi + re[j];
        xi = L.x * xi + L.y * xr + im[j];
        xr = nr;
        re[j] = xr;   // reuse as output staging
        im[j] = xi;
    }
    #pragma unroll
    for (int q = 0; q < 4; ++q) {
        *(float4*)&Xs[baseRe + q * 4] = make_float4(re[q*4+0], re[q*4+1], re[q*4+2], re[q*4+3]);
        *(float4*)&Xs[baseIm + q * 4] = make_float4(im[q*4+0], im[q*4+1], im[q*4+2], im[q*4+3]);
    }
}

// ---------- launch ----------

extern "C" void kernel_launch(void* const* d_in, const int* in_sizes, int n_in,
                              void* d_out, int out_size, void* d_ws, size_t ws_size,
                              hipStream_t stream) {
    const float* u    = (const float*)d_in[0];
    const float* lre  = (const float*)d_in[1];
    const float* lim  = (const float*)d_in[2];
    const float* Bre  = (const float*)d_in[3];
    const float* Bim  = (const float*)d_in[4];
    const float* Cre  = (const float*)d_in[5];
    const float* Cim  = (const float*)d_in[6];
    const float* Dv   = (const float*)d_in[7];
    const float* logd = (const float*)d_in[8];
    float* out = (float*)d_out;

    char* ws = (char*)d_ws;
    float*  W1   = (float*)ws;                          // 1 MB
    float*  W2   = (float*)(ws + (1 << 20));            // 1 MB
    float2* lamb = (float2*)(ws + (2 << 20));           // 2 KB
    float*  Xs   = (float*)(ws + (2 << 20) + 4096);     // 64 MB

    prep_w1_k<<<(PP * HH) / 256, 256, 0, stream>>>(lre, lim, logd, Bre, Bim, W1, lamb);
    prep_w2_k<<<(N2P * HH) / 256, 256, 0, stream>>>(Cre, Cim, W2);

    // GEMM1: u -> T1 (transposed intermediate, in d_out)
    gemm1_t<<<dim3(MTOT / 64, N2P / 64), 256, 0, stream>>>(u, W1, out);
    // scan: T1 -> Xs (same transposed layout)
    scan_k<<<BB * PP, 256, 0, stream>>>(out, Xs, lamb);
    // GEMM2: Xs -> y (+ D*u epilogue), natural (B,L,H) layout
    gemm2_t<<<dim3(HH / 64, MTOT / 64), 256, 0, stream>>>(Xs, W2, out, u, Dv);
}

// Round 3
// 121.303 us; speedup vs baseline: 6.0944x; 4.1540x over previous
//
#include <hip/hip_runtime.h>
#include <math.h>

#define HH 512
#define PP 256
#define LSEQ 4096
#define BB 8
#define MTOT (BB*LSEQ)   // 32768
#define N2P 512          // 2*P

typedef __attribute__((ext_vector_type(8))) short bf16x8;
typedef __attribute__((ext_vector_type(4))) float f32x4;
typedef __attribute__((ext_vector_type(8))) unsigned short u16x8;
typedef __attribute__((ext_vector_type(4))) unsigned short u16x4;

__device__ inline unsigned short f2bf(float f) {
    union { float f; unsigned int u; } v; v.f = f;
    unsigned int u = v.u;
    u += 0x7fffu + ((u >> 16) & 1u);
    return (unsigned short)(u >> 16);
}
__device__ inline float bf2f(unsigned short h) {
    union { unsigned int u; float f; } v; v.u = ((unsigned int)h) << 16;
    return v.f;
}

// XOR-swizzle: byte bits 4-6, mixes both low and mid row bits so that both
// row-strided reads (rows = lane&15) and col-strided scatter writes spread.
#define SWZ(row) (((((row) & 7) ^ (((row) >> 3) & 7)) << 4))

// ---------- prep: W1t[r][h] bf16 (r = p re | P+p im), lambda_bar ----------
__global__ void prep_w1_k(const float* __restrict__ lre, const float* __restrict__ lim,
                          const float* __restrict__ logd,
                          const float* __restrict__ Bre, const float* __restrict__ Bim,
                          unsigned short* __restrict__ W1t, float2* __restrict__ lamb) {
    int idx = blockIdx.x * 256 + threadIdx.x;   // over P*H
    if (idx >= PP * HH) return;
    int p = idx >> 9;
    int h = idx & (HH - 1);
    float delta = expf(logd[p]);
    float lr = lre[p], li = lim[p];
    float er = expf(lr * delta);
    float th = li * delta;
    float lbr = er * cosf(th), lbi = er * sinf(th);
    if (h == 0) lamb[p] = make_float2(lbr, lbi);
    float a = lbr - 1.0f, b = lbi;
    float n2 = lr * lr + li * li;
    float gr = (a * lr + b * li) / n2;
    float gi = (b * lr - a * li) / n2;
    float br = Bre[idx], bi = Bim[idx];
    W1t[(size_t)p * HH + h]        = f2bf(gr * br - gi * bi);
    W1t[(size_t)(PP + p) * HH + h] = f2bf(gr * bi + gi * br);
}

// ---------- prep: W2t[h][k] bf16: k<P -> 2*C_re[h][k]; else -2*C_im ----------
__global__ void prep_w2_k(const float* __restrict__ Cre, const float* __restrict__ Cim,
                          unsigned short* __restrict__ W2t) {
    int idx = blockIdx.x * 256 + threadIdx.x;   // over H*2P
    if (idx >= HH * N2P) return;
    int h = idx >> 9;
    int k = idx & 511;
    float v = (k < PP) ? 2.0f * Cre[(size_t)h * PP + k]
                       : -2.0f * Cim[(size_t)h * PP + (k - PP)];
    W2t[(size_t)h * N2P + k] = f2bf(v);
}

// ---------- GEMM1: T1[r][m] = sum_h u[m][h] * W1t[r][h]  (bf16 MFMA) ----------
// M-dim = m (32768), N-dim = r (512), K = h (512). Output written transposed.
__global__ __launch_bounds__(256) void gemm1_k(const float* __restrict__ u,
                                               const unsigned short* __restrict__ W1t,
                                               unsigned short* __restrict__ T1) {
    __shared__ char smem[32768];
    char* Asw = smem;            // [128 m][64 k] bf16, swizzled
    char* Bsw = smem + 16384;    // [128 r][64 k] bf16, swizzled
    const int tid = threadIdx.x;
    const int m0 = blockIdx.y * 128;
    const int n0 = blockIdx.x * 128;
    const int wave = tid >> 6, lane = tid & 63;
    const int wm = (wave >> 1) * 64, wn = (wave & 1) * 64;

    f32x4 acc[4][4] = {};

    for (int k0 = 0; k0 < 512; k0 += 64) {
        // stage A: u fp32 -> bf16, natural [m][k]
        #pragma unroll
        for (int it = 0; it < 4; ++it) {
            int idx = it * 256 + tid;       // 0..1023
            int row = idx >> 3, c = idx & 7;
            const float4 v0 = *(const float4*)&u[(size_t)(m0 + row) * HH + k0 + c * 8];
            const float4 v1 = *(const float4*)&u[(size_t)(m0 + row) * HH + k0 + c * 8 + 4];
            bf16x8 pk;
            pk[0] = (short)f2bf(v0.x); pk[1] = (short)f2bf(v0.y);
            pk[2] = (short)f2bf(v0.z); pk[3] = (short)f2bf(v0.w);
            pk[4] = (short)f2bf(v1.x); pk[5] = (short)f2bf(v1.y);
            pk[6] = (short)f2bf(v1.z); pk[7] = (short)f2bf(v1.w);
            *(bf16x8*)(Asw + row * 128 + ((c * 16) ^ SWZ(row))) = pk;
        }
        // stage B: W1t bf16 natural [r][k]
        #pragma unroll
        for (int it = 0; it < 4; ++it) {
            int idx = it * 256 + tid;
            int row = idx >> 3, c = idx & 7;
            bf16x8 pk = *(const bf16x8*)&W1t[(size_t)(n0 + row) * HH + k0 + c * 8];
            *(bf16x8*)(Bsw + row * 128 + ((c * 16) ^ SWZ(row))) = pk;
        }
        __syncthreads();

        bf16x8 af[4][2], bfr[4][2];
        #pragma unroll
        for (int f = 0; f < 4; ++f) {
            #pragma unroll
            for (int kk = 0; kk < 2; ++kk) {
                int ar = wm + f * 16 + (lane & 15);
                af[f][kk]  = *(const bf16x8*)(Asw + ar * 128 + ((kk * 64 + (lane >> 4) * 16) ^ SWZ(ar)));
                int br = wn + f * 16 + (lane & 15);
                bfr[f][kk] = *(const bf16x8*)(Bsw + br * 128 + ((kk * 64 + (lane >> 4) * 16) ^ SWZ(br)));
            }
        }
        #pragma unroll
        for (int fm = 0; fm < 4; ++fm)
            #pragma unroll
            for (int fn = 0; fn < 4; ++fn)
                #pragma unroll
                for (int kk = 0; kk < 2; ++kk)
                    acc[fm][fn] = __builtin_amdgcn_mfma_f32_16x16x32_bf16(
                        af[fm][kk], bfr[fn][kk], acc[fm][fn], 0, 0, 0);
        __syncthreads();
    }

    // C-write transposed: T1[r][m], 4 consecutive m per lane -> 8B stores
    #pragma unroll
    for (int fm = 0; fm < 4; ++fm) {
        #pragma unroll
        for (int fn = 0; fn < 4; ++fn) {
            int r = n0 + wn + fn * 16 + (lane & 15);
            int m = m0 + wm + fm * 16 + ((lane >> 4) << 2);
            u16x4 pk;
            pk[0] = f2bf(acc[fm][fn][0]); pk[1] = f2bf(acc[fm][fn][1]);
            pk[2] = f2bf(acc[fm][fn][2]); pk[3] = f2bf(acc[fm][fn][3]);
            *(u16x4*)&T1[(size_t)r * MTOT + m] = pk;
        }
    }
}

// ---------- GEMM2: y[m][h] = sum_k Xs[k][m] * W2t[h][k] + D[h]*u[m][h] ----------
__global__ __launch_bounds__(256) void gemm2_k(const unsigned short* __restrict__ Xs,
                                               const unsigned short* __restrict__ W2t,
                                               float* __restrict__ y,
                                               const float* __restrict__ u,
                                               const float* __restrict__ D) {
    __shared__ char smem[65536];
    char* Asw = smem;            // [128 m][64 k] bf16, swizzled (transposed from Xs)
    char* Bsw = smem + 16384;    // [128 h][64 k] bf16, swizzled
    float* epi = (float*)smem;   // 64KB epilogue: wave w at w*4096 floats, [64][64]
    const int tid = threadIdx.x;
    const int m0 = blockIdx.y * 128;
    const int n0 = blockIdx.x * 128;
    const int wave = tid >> 6, lane = tid & 63;
    const int wm = (wave >> 1) * 64, wn = (wave & 1) * 64;

    f32x4 acc[4][4] = {};

    for (int k0 = 0; k0 < 512; k0 += 64) {
        // stage A: Xs[k][m] -> Asw[m][k] (coalesced reads, b16 scatter writes)
        #pragma unroll
        for (int it = 0; it < 4; ++it) {
            int idx = it * 256 + tid;      // 0..1023: kr 0..63, c 0..15
            int kr = idx >> 4, c = idx & 15;
            u16x8 v = *(const u16x8*)&Xs[(size_t)(k0 + kr) * MTOT + m0 + c * 8];
            #pragma unroll
            for (int j = 0; j < 8; ++j) {
                int m = c * 8 + j;
                *(unsigned short*)(Asw + m * 128 + ((kr * 2) ^ SWZ(m))) = v[j];
            }
        }
        // stage B: W2t natural [h][k]
        #pragma unroll
        for (int it = 0; it < 4; ++it) {
            int idx = it * 256 + tid;
            int row = idx >> 3, c = idx & 7;
            bf16x8 pk = *(const bf16x8*)&W2t[(size_t)(n0 + row) * N2P + k0 + c * 8];
            *(bf16x8*)(Bsw + row * 128 + ((c * 16) ^ SWZ(row))) = pk;
        }
        __syncthreads();

        bf16x8 af[4][2], bfr[4][2];
        #pragma unroll
        for (int f = 0; f < 4; ++f) {
            #pragma unroll
            for (int kk = 0; kk < 2; ++kk) {
                int ar = wm + f * 16 + (lane & 15);
                af[f][kk]  = *(const bf16x8*)(Asw + ar * 128 + ((kk * 64 + (lane >> 4) * 16) ^ SWZ(ar)));
                int br = wn + f * 16 + (lane & 15);
                bfr[f][kk] = *(const bf16x8*)(Bsw + br * 128 + ((kk * 64 + (lane >> 4) * 16) ^ SWZ(br)));
            }
        }
        #pragma unroll
        for (int fm = 0; fm < 4; ++fm)
            #pragma unroll
            for (int fn = 0; fn < 4; ++fn)
                #pragma unroll
                for (int kk = 0; kk < 2; ++kk)
                    acc[fm][fn] = __builtin_amdgcn_mfma_f32_16x16x32_bf16(
                        af[fm][kk], bfr[fn][kk], acc[fm][fn], 0, 0, 0);
        __syncthreads();
    }

    // epilogue: fragments -> LDS [m][h] per wave, then coalesced row stores
    float* myepi = epi + wave * 4096;
    #pragma unroll
    for (int fm = 0; fm < 4; ++fm) {
        #pragma unroll
        for (int fn = 0; fn < 4; ++fn) {
            int ml = fm * 16 + ((lane >> 4) << 2);
            int hl = fn * 16 + (lane & 15);
            #pragma unroll
            for (int i = 0; i < 4; ++i)
                myepi[(ml + i) * 64 + hl] = acc[fm][fn][i];
        }
    }
    __syncthreads();

    #pragma unroll
    for (int it = 0; it < 16; ++it) {
        int idx = it * 256 + tid;          // 0..4095: row ml 0..127, chunk c 0..31
        int ml = idx >> 5, c = idx & 31;
        int w = ((ml >> 6) << 1) + (c >> 4);
        const float4 v = *(const float4*)(epi + w * 4096 + (ml & 63) * 64 + (c & 15) * 4);
        int grow = m0 + ml, gcol = n0 + c * 4;
        const float4 uv = *(const float4*)&u[(size_t)grow * HH + gcol];
        const float4 dv = *(const float4*)&D[gcol];
        float4 o = make_float4(v.x + dv.x * uv.x, v.y + dv.y * uv.y,
                               v.z + dv.z * uv.z, v.w + dv.w * uv.w);
        *(float4*)&y[(size_t)grow * HH + gcol] = o;
    }
}

// ---------- coalesced chunked complex scan (bf16 in/out, fp32 internal) ----------
__global__ __launch_bounds__(256) void scan_k(const unsigned short* __restrict__ T1,
                                              unsigned short* __restrict__ Xs,
                                              const float2* __restrict__ lamb) {
    const int b = blockIdx.x >> 8;
    const int p = blockIdx.x & 255;
    const int t = threadIdx.x;
    const float2 L = lamb[p];

    const size_t baseRe = (size_t)p * MTOT + (size_t)b * LSEQ + t * 16;
    const size_t baseIm = (size_t)(PP + p) * MTOT + (size_t)b * LSEQ + t * 16;

    u16x8 r0 = *(const u16x8*)&T1[baseRe];
    u16x8 r1 = *(const u16x8*)&T1[baseRe + 8];
    u16x8 i0 = *(const u16x8*)&T1[baseIm];
    u16x8 i1 = *(const u16x8*)&T1[baseIm + 8];

    float re[16], im[16];
    #pragma unroll
    for (int j = 0; j < 8; ++j) {
        re[j] = bf2f(r0[j]); re[8 + j] = bf2f(r1[j]);
        im[j] = bf2f(i0[j]); im[8 + j] = bf2f(i1[j]);
    }

    float sr = 0.f, si = 0.f;
    #pragma unroll
    for (int j = 0; j < 16; ++j) {
        float nsr = L.x * sr - L.y * si + re[j];
        si = L.x * si + L.y * sr + im[j];
        sr = nsr;
    }

    __shared__ float cr[256], ci[256];
    cr[t] = sr; ci[t] = si;
    __syncthreads();

    float wr = L.x, wi = L.y;
    #pragma unroll
    for (int q = 0; q < 4; ++q) { float nr = wr * wr - wi * wi; wi = 2.f * wr * wi; wr = nr; }

    for (int off = 1; off < 256; off <<= 1) {
        float pr = 0.f, pi = 0.f;
        const bool has = (t >= off);
        if (has) { pr = cr[t - off]; pi = ci[t - off]; }
        __syncthreads();
        if (has) {
            sr += wr * pr - wi * pi;
            si += wr * pi + wi * pr;
            cr[t] = sr; ci[t] = si;
        }
        __syncthreads();
        float nr = wr * wr - wi * wi; wi = 2.f * wr * wi; wr = nr;
    }

    float xr = 0.f, xi = 0.f;
    if (t > 0) { xr = cr[t - 1]; xi = ci[t - 1]; }

    u16x8 o0, o1, o2, o3;
    #pragma unroll
    for (int j = 0; j < 16; ++j) {
        float nr = L.x * xr - L.y * xi + re[j];
        xi = L.x * xi + L.y * xr + im[j];
        xr = nr;
        if (j < 8) { o0[j] = f2bf(xr); o2[j] = f2bf(xi); }
        else       { o1[j - 8] = f2bf(xr); o3[j - 8] = f2bf(xi); }
    }
    *(u16x8*)&Xs[baseRe]     = o0;
    *(u16x8*)&Xs[baseRe + 8] = o1;
    *(u16x8*)&Xs[baseIm]     = o2;
    *(u16x8*)&Xs[baseIm + 8] = o3;
}

// ---------- launch ----------

extern "C" void kernel_launch(void* const* d_in, const int* in_sizes, int n_in,
                              void* d_out, int out_size, void* d_ws, size_t ws_size,
                              hipStream_t stream) {
    const float* u    = (const float*)d_in[0];
    const float* lre  = (const float*)d_in[1];
    const float* lim  = (const float*)d_in[2];
    const float* Bre  = (const float*)d_in[3];
    const float* Bim  = (const float*)d_in[4];
    const float* Cre  = (const float*)d_in[5];
    const float* Cim  = (const float*)d_in[6];
    const float* Dv   = (const float*)d_in[7];
    const float* logd = (const float*)d_in[8];
    float* out = (float*)d_out;

    char* ws = (char*)d_ws;
    unsigned short* W1t  = (unsigned short*)ws;                     // 512 KB
    unsigned short* W2t  = (unsigned short*)(ws + (512 << 10));     // 512 KB
    float2*         lamb = (float2*)(ws + (1 << 20));               // 2 KB
    unsigned short* Xs   = (unsigned short*)(ws + (1 << 20) + 4096);// 32 MB

    unsigned short* T1 = (unsigned short*)d_out;  // 32 MB bf16, overwritten by y later

    prep_w1_k<<<(PP * HH) / 256, 256, 0, stream>>>(lre, lim, logd, Bre, Bim, W1t, lamb);
    prep_w2_k<<<(HH * N2P) / 256, 256, 0, stream>>>(Cre, Cim, W2t);

    // GEMM1: u (fp32) x W1t (bf16) -> T1[r][m] bf16
    gemm1_k<<<dim3(N2P / 128, MTOT / 128), 256, 0, stream>>>(u, W1t, T1);
    // scan: T1 -> Xs (same transposed layout, bf16)
    scan_k<<<BB * PP, 256, 0, stream>>>(T1, Xs, lamb);
    // GEMM2: Xs x W2t -> y fp32 (+ D*u epilogue)
    gemm2_k<<<dim3(HH / 128, MTOT / 128), 256, 0, stream>>>(Xs, W2t, out, u, Dv);
}

// Round 4
// 97.632 us; speedup vs baseline: 7.5720x; 1.2425x over previous
//
#include <hip/hip_runtime.h>
#include <hip/hip_bf16.h>
#include <math.h>

#define HH 512
#define PP 256
#define LSEQ 4096
#define BB 8
#define MTOT (BB*LSEQ)   // 32768
#define N2P 512          // 2*P

typedef __attribute__((ext_vector_type(8))) short bf16x8;
typedef __attribute__((ext_vector_type(4))) float f32x4;
typedef __attribute__((ext_vector_type(8))) unsigned short u16x8;
typedef __attribute__((ext_vector_type(4))) unsigned short u16x4;

// XOR-swizzle on byte bits 4-6 of each 128B LDS row
#define SWZ(row) (((((row) & 7) ^ (((row) >> 3) & 7)) << 4))

__device__ inline unsigned short f2b(float x) {
    return __builtin_bit_cast(unsigned short, __float2bfloat16(x));
}
__device__ inline float b2f(unsigned short h) {
    union { unsigned int u; float f; } v; v.u = ((unsigned int)h) << 16;
    return v.f;
}

// async global->LDS, 16B per lane; dest = lds_base + lane*16
#define GLOAD16(gp, lp) __builtin_amdgcn_global_load_lds( \
    (const __attribute__((address_space(1))) unsigned int*)(gp), \
    (__attribute__((address_space(3))) unsigned int*)(lp), 16, 0, 0)

// swizzled-panel byte offset for element (row r in [0,512), k in [0,512))
// panels: [r>>7][k>>6] of 128x64 bf16 = 16KB, interior = LDS image
__device__ inline size_t panel_off(int r, int k) {
    int nblk = r >> 7, rl = r & 127;
    int kblk = k >> 6, kl = k & 63;
    int c = kl >> 3, j = kl & 7;
    return (size_t)(nblk * 8 + kblk) * 16384 + rl * 128 + ((c * 16) ^ SWZ(rl)) + j * 2;
}

// ---------- prep: W1 panels (r = p re | P+p im over h), lambda_bar ----------
__global__ void prep_w1_k(const float* __restrict__ lre, const float* __restrict__ lim,
                          const float* __restrict__ logd,
                          const float* __restrict__ Bre, const float* __restrict__ Bim,
                          char* __restrict__ W1s, float2* __restrict__ lamb) {
    int idx = blockIdx.x * 256 + threadIdx.x;   // over P*H
    if (idx >= PP * HH) return;
    int p = idx >> 9;
    int h = idx & (HH - 1);
    float delta = expf(logd[p]);
    float lr = lre[p], li = lim[p];
    float er = expf(lr * delta);
    float th = li * delta;
    float lbr = er * cosf(th), lbi = er * sinf(th);
    if (h == 0) lamb[p] = make_float2(lbr, lbi);
    float a = lbr - 1.0f, b = lbi;
    float n2 = lr * lr + li * li;
    float gr = (a * lr + b * li) / n2;
    float gi = (b * lr - a * li) / n2;
    float br = Bre[idx], bi = Bim[idx];
    *(unsigned short*)(W1s + panel_off(p, h))      = f2b(gr * br - gi * bi);
    *(unsigned short*)(W1s + panel_off(PP + p, h)) = f2b(gr * bi + gi * br);
}

// ---------- prep: W2 panels over (h, k): k<P -> 2*C_re[h][k]; else -2*C_im ----------
__global__ void prep_w2_k(const float* __restrict__ Cre, const float* __restrict__ Cim,
                          char* __restrict__ W2s) {
    int idx = blockIdx.x * 256 + threadIdx.x;   // over H*2P
    if (idx >= HH * N2P) return;
    int h = idx >> 9;
    int k = idx & 511;
    float v = (k < PP) ? 2.0f * Cre[(size_t)h * PP + k]
                       : -2.0f * Cim[(size_t)h * PP + (k - PP)];
    *(unsigned short*)(W2s + panel_off(h, k)) = f2b(v);
}

// shared MFMA tile compute: 128x128 per block, 4 waves, 64x64 per wave
#define TILE_COMPUTE(ABUF, BBUF) { \
    bf16x8 af[4][2], bfr[4][2]; \
    _Pragma("unroll") for (int f = 0; f < 4; ++f) { \
      _Pragma("unroll") for (int kk = 0; kk < 2; ++kk) { \
        int ar = wm + f * 16 + (lane & 15); \
        af[f][kk]  = *(const bf16x8*)((ABUF) + ar * 128 + ((kk * 64 + (lane >> 4) * 16) ^ SWZ(ar))); \
        int br = wn + f * 16 + (lane & 15); \
        bfr[f][kk] = *(const bf16x8*)((BBUF) + br * 128 + ((kk * 64 + (lane >> 4) * 16) ^ SWZ(br))); } } \
    _Pragma("unroll") for (int fm = 0; fm < 4; ++fm) { \
      _Pragma("unroll") for (int fn = 0; fn < 4; ++fn) { \
        _Pragma("unroll") for (int kk = 0; kk < 2; ++kk) { \
          acc[fm][fn] = __builtin_amdgcn_mfma_f32_16x16x32_bf16(af[fm][kk], bfr[fn][kk], acc[fm][fn], 0, 0, 0); } } } }

// ---------- GEMM1: T1[r][m] = sum_h u[m][h] * W1[r][h]  (bf16 MFMA) ----------
__global__ __launch_bounds__(256) void gemm1_k(const float* __restrict__ u,
                                               const char* __restrict__ W1s,
                                               unsigned short* __restrict__ T1) {
    __shared__ char smem[65536];
    const int tid = threadIdx.x, wave = tid >> 6, lane = tid & 63;
    const int swz = (blockIdx.x & 7) * 128 + (blockIdx.x >> 3);   // XCD-chunked, bijective
    const int m0 = (swz >> 2) * 128;
    const int nblk = swz & 3, n0 = nblk * 128;
    const int wm = (wave >> 1) * 64, wn = (wave & 1) * 64;
    const int arow = tid >> 3, acol = tid & 7;

    float4 av0[4], av1[4];
    f32x4 acc[4][4] = {};

#define G1_A_LOAD(K0) { \
    _Pragma("unroll") for (int it = 0; it < 4; ++it) { \
        int row = it * 32 + arow; \
        const float* src = &u[(size_t)(m0 + row) * HH + (K0) + acol * 8]; \
        av0[it] = *(const float4*)src; av1[it] = *(const float4*)(src + 4); } }

#define G1_A_WRITE(ABUF) { \
    _Pragma("unroll") for (int it = 0; it < 4; ++it) { \
        int row = it * 32 + arow; \
        bf16x8 pk; \
        pk[0] = (short)f2b(av0[it].x); pk[1] = (short)f2b(av0[it].y); \
        pk[2] = (short)f2b(av0[it].z); pk[3] = (short)f2b(av0[it].w); \
        pk[4] = (short)f2b(av1[it].x); pk[5] = (short)f2b(av1[it].y); \
        pk[6] = (short)f2b(av1[it].z); pk[7] = (short)f2b(av1[it].w); \
        *(bf16x8*)((ABUF) + row * 128 + ((acol * 16) ^ SWZ(row))) = pk; } }

#define G1_B_GLOAD(K0, BBUF) { \
    const char* panel = W1s + (size_t)(nblk * 8 + ((K0) >> 6)) * 16384 + wave * 4096 + lane * 16; \
    _Pragma("unroll") for (int q = 0; q < 4; ++q) \
        GLOAD16(panel + q * 1024, (BBUF) + wave * 4096 + q * 1024); }

    char* A0 = smem;          char* B0 = smem + 16384;
    char* A1 = smem + 32768;  char* B1 = smem + 49152;

    G1_A_LOAD(0); G1_B_GLOAD(0, B0); G1_A_WRITE(A0);
    asm volatile("s_waitcnt vmcnt(0)" ::: "memory");
    __syncthreads();

    #pragma unroll
    for (int t = 0; t < 8; ++t) {
        char* Ac = (t & 1) ? A1 : A0; char* Bc = (t & 1) ? B1 : B0;
        char* An = (t & 1) ? A0 : A1; char* Bn = (t & 1) ? B0 : B1;
        if (t < 7) { G1_A_LOAD((t + 1) * 64); G1_B_GLOAD((t + 1) * 64, Bn); }
        TILE_COMPUTE(Ac, Bc);
        if (t < 7) { G1_A_WRITE(An); }
        asm volatile("s_waitcnt vmcnt(0)" ::: "memory");
        __syncthreads();
    }

    // C-write transposed: T1[r][m], 4 consecutive m per lane -> 8B stores
    #pragma unroll
    for (int fm = 0; fm < 4; ++fm) {
        #pragma unroll
        for (int fn = 0; fn < 4; ++fn) {
            int r = n0 + wn + fn * 16 + (lane & 15);
            int m = m0 + wm + fm * 16 + ((lane >> 4) << 2);
            u16x4 pk;
            pk[0] = f2b(acc[fm][fn][0]); pk[1] = f2b(acc[fm][fn][1]);
            pk[2] = f2b(acc[fm][fn][2]); pk[3] = f2b(acc[fm][fn][3]);
            *(u16x4*)&T1[(size_t)r * MTOT + m] = pk;
        }
    }
}

// ---------- GEMM2: y[m][h] = sum_k Xs[k][m] * W2[h][k] + D[h]*u[m][h] ----------
__global__ __launch_bounds__(256) void gemm2_k(const unsigned short* __restrict__ Xs,
                                               const char* __restrict__ W2s,
                                               float* __restrict__ y,
                                               const float* __restrict__ u,
                                               const float* __restrict__ D) {
    __shared__ char smem[65536];
    const int tid = threadIdx.x, wave = tid >> 6, lane = tid & 63;
    const int swz = (blockIdx.x & 7) * 128 + (blockIdx.x >> 3);
    const int m0 = (swz >> 2) * 128;
    const int nblk = swz & 3, n0 = nblk * 128;
    const int wm = (wave >> 1) * 64, wn = (wave & 1) * 64;
    const int kg = tid >> 4, mc = tid & 15;

    u16x8 xv[4];
    f32x4 acc[4][4] = {};

#define G2_A_LOAD(K0) { \
    _Pragma("unroll") for (int kk = 0; kk < 4; ++kk) \
        xv[kk] = *(const u16x8*)&Xs[(size_t)((K0) + kg * 4 + kk) * MTOT + m0 + mc * 8]; }

#define G2_A_WRITE(ABUF) { \
    _Pragma("unroll") for (int j = 0; j < 8; ++j) { \
        int row = mc * 8 + j; \
        u16x4 o; o[0] = xv[0][j]; o[1] = xv[1][j]; o[2] = xv[2][j]; o[3] = xv[3][j]; \
        *(u16x4*)((ABUF) + row * 128 + ((kg * 8) ^ SWZ(row))) = o; } }

#define G2_B_GLOAD(K0, BBUF) { \
    const char* panel = W2s + (size_t)(nblk * 8 + ((K0) >> 6)) * 16384 + wave * 4096 + lane * 16; \
    _Pragma("unroll") for (int q = 0; q < 4; ++q) \
        GLOAD16(panel + q * 1024, (BBUF) + wave * 4096 + q * 1024); }

    char* A0 = smem;          char* B0 = smem + 16384;
    char* A1 = smem + 32768;  char* B1 = smem + 49152;

    G2_A_LOAD(0); G2_B_GLOAD(0, B0); G2_A_WRITE(A0);
    asm volatile("s_waitcnt vmcnt(0)" ::: "memory");
    __syncthreads();

    #pragma unroll
    for (int t = 0; t < 8; ++t) {
        char* Ac = (t & 1) ? A1 : A0; char* Bc = (t & 1) ? B1 : B0;
        char* An = (t & 1) ? A0 : A1; char* Bn = (t & 1) ? B0 : B1;
        if (t < 7) { G2_A_LOAD((t + 1) * 64); G2_B_GLOAD((t + 1) * 64, Bn); }
        TILE_COMPUTE(Ac, Bc);
        if (t < 7) { G2_A_WRITE(An); }
        asm volatile("s_waitcnt vmcnt(0)" ::: "memory");
        __syncthreads();
    }

    // epilogue: fragments -> LDS [m][h] per wave, then coalesced row stores (+ D*u)
    float* epi = (float*)smem;
    float* myepi = epi + wave * 4096;
    #pragma unroll
    for (int fm = 0; fm < 4; ++fm) {
        #pragma unroll
        for (int fn = 0; fn < 4; ++fn) {
            int ml = fm * 16 + ((lane >> 4) << 2);
            int hl = fn * 16 + (lane & 15);
            #pragma unroll
            for (int i = 0; i < 4; ++i)
                myepi[(ml + i) * 64 + hl] = acc[fm][fn][i];
        }
    }
    __syncthreads();

    #pragma unroll
    for (int it = 0; it < 16; ++it) {
        int idx = it * 256 + tid;          // 0..4095: row ml 0..127, chunk c 0..31
        int ml = idx >> 5, c = idx & 31;
        int w = ((ml >> 6) << 1) + (c >> 4);
        const float4 v = *(const float4*)(epi + w * 4096 + (ml & 63) * 64 + (c & 15) * 4);
        int grow = m0 + ml, gcol = n0 + c * 4;
        const float4 uv = *(const float4*)&u[(size_t)grow * HH + gcol];
        const float4 dv = *(const float4*)&D[gcol];
        float4 o = make_float4(v.x + dv.x * uv.x, v.y + dv.y * uv.y,
                               v.z + dv.z * uv.z, v.w + dv.w * uv.w);
        *(float4*)&y[(size_t)grow * HH + gcol] = o;
    }
}

// ---------- coalesced chunked complex scan (bf16 in/out, fp32 internal) ----------
__global__ __launch_bounds__(256) void scan_k(const unsigned short* __restrict__ T1,
                                              unsigned short* __restrict__ Xs,
                                              const float2* __restrict__ lamb) {
    const int b = blockIdx.x >> 8;
    const int p = blockIdx.x & 255;
    const int t = threadIdx.x;
    const float2 L = lamb[p];

    const size_t baseRe = (size_t)p * MTOT + (size_t)b * LSEQ + t * 16;
    const size_t baseIm = (size_t)(PP + p) * MTOT + (size_t)b * LSEQ + t * 16;

    u16x8 r0 = *(const u16x8*)&T1[baseRe];
    u16x8 r1 = *(const u16x8*)&T1[baseRe + 8];
    u16x8 i0 = *(const u16x8*)&T1[baseIm];
    u16x8 i1 = *(const u16x8*)&T1[baseIm + 8];

    float re[16], im[16];
    #pragma unroll
    for (int j = 0; j < 8; ++j) {
        re[j] = b2f(r0[j]); re[8 + j] = b2f(r1[j]);
        im[j] = b2f(i0[j]); im[8 + j] = b2f(i1[j]);
    }

    float sr = 0.f, si = 0.f;
    #pragma unroll
    for (int j = 0; j < 16; ++j) {
        float nsr = L.x * sr - L.y * si + re[j];
        si = L.x * si + L.y * sr + im[j];
        sr = nsr;
    }

    __shared__ float cr[256], ci[256];
    cr[t] = sr; ci[t] = si;
    __syncthreads();

    float wr = L.x, wi = L.y;
    #pragma unroll
    for (int q = 0; q < 4; ++q) { float nr = wr * wr - wi * wi; wi = 2.f * wr * wi; wr = nr; }

    for (int off = 1; off < 256; off <<= 1) {
        float pr = 0.f, pi = 0.f;
        const bool has = (t >= off);
        if (has) { pr = cr[t - off]; pi = ci[t - off]; }
        __syncthreads();
        if (has) {
            sr += wr * pr - wi * pi;
            si += wr * pi + wi * pr;
            cr[t] = sr; ci[t] = si;
        }
        __syncthreads();
        float nr = wr * wr - wi * wi; wi = 2.f * wr * wi; wr = nr;
    }

    float xr = 0.f, xi = 0.f;
    if (t > 0) { xr = cr[t - 1]; xi = ci[t - 1]; }

    u16x8 o0, o1, o2, o3;
    #pragma unroll
    for (int j = 0; j < 16; ++j) {
        float nr = L.x * xr - L.y * xi + re[j];
        xi = L.x * xi + L.y * xr + im[j];
        xr = nr;
        if (j < 8) { o0[j] = f2b(xr); o2[j] = f2b(xi); }
        else       { o1[j - 8] = f2b(xr); o3[j - 8] = f2b(xi); }
    }
    *(u16x8*)&Xs[baseRe]     = o0;
    *(u16x8*)&Xs[baseRe + 8] = o1;
    *(u16x8*)&Xs[baseIm]     = o2;
    *(u16x8*)&Xs[baseIm + 8] = o3;
}

// ---------- launch ----------

extern "C" void kernel_launch(void* const* d_in, const int* in_sizes, int n_in,
                              void* d_out, int out_size, void* d_ws, size_t ws_size,
                              hipStream_t stream) {
    const float* u    = (const float*)d_in[0];
    const float* lre  = (const float*)d_in[1];
    const float* lim  = (const float*)d_in[2];
    const float* Bre  = (const float*)d_in[3];
    const float* Bim  = (const float*)d_in[4];
    const float* Cre  = (const float*)d_in[5];
    const float* Cim  = (const float*)d_in[6];
    const float* Dv   = (const float*)d_in[7];
    const float* logd = (const float*)d_in[8];
    float* out = (float*)d_out;

    char* ws = (char*)d_ws;
    char*           W1s  = ws;                                      // 512 KB (swizzled panels)
    char*           W2s  = ws + (512 << 10);                        // 512 KB
    float2*         lamb = (float2*)(ws + (1 << 20));               // 2 KB
    unsigned short* Xs   = (unsigned short*)(ws + (1 << 20) + 4096);// 32 MB

    unsigned short* T1 = (unsigned short*)d_out;  // 32 MB bf16, overwritten by y later

    prep_w1_k<<<(PP * HH) / 256, 256, 0, stream>>>(lre, lim, logd, Bre, Bim, W1s, lamb);
    prep_w2_k<<<(HH * N2P) / 256, 256, 0, stream>>>(Cre, Cim, W2s);

    // GEMM1: u (fp32) x W1 (bf16 panels) -> T1[r][m] bf16
    gemm1_k<<<1024, 256, 0, stream>>>(u, W1s, T1);
    // scan: T1 -> Xs (same transposed layout, bf16)
    scan_k<<<BB * PP, 256, 0, stream>>>(T1, Xs, lamb);
    // GEMM2: Xs x W2 -> y fp32 (+ D*u epilogue)
    gemm2_k<<<1024, 256, 0, stream>>>(Xs, W2s, out, u, Dv);
}